// Round 10
// baseline (420.686 us; speedup 1.0000x reference)
//
#include <hip/hip_runtime.h>
#include <hip/hip_bf16.h>
#include <math.h>

typedef unsigned int u32;
typedef unsigned short u16;
typedef unsigned long long u64;
typedef int   v4i __attribute__((ext_vector_type(4)));
typedef float v4f __attribute__((ext_vector_type(4)));
typedef unsigned long long v2u __attribute__((ext_vector_type(2)));

#define NSEG 49
#define SEGW 2048
#define SEGSHIFT 11
#define XEPS 1.4901161e-08f  // 2^-26: below this, q == 1.0f bit-exactly
#define NOVF 4096

// ---- tier A: 8-byte records (single dwordx2 store per edge)
#define NBLK8 512
#define CHV8 7813            // ceil(4,000,000 / 512) int4-vectors per block
#define SCT8 1024
#define CAP8 720u            // mean 637.8, +3.3 sigma; valve catches the tail
#define SPLIT_HI 64          // step blocks per segment (preferred: 3136 blocks)
#define SPLIT_LO 32          // proven fallback (1568 blocks)
#define SLIMCH 16            // sp-values per block in slim (k>=2) launches

// ---- tier B: 6-byte records (round-6 proven layout, smaller ws)
#define CHV6 8192
#define SCT6 512
#define CAP6 832u
#define SPLIT6 24

// ============ init: s=1-x0, x=x0, r=0; flags[0]=1, rest 0 (flags[31]=ovf cursor) ============
__global__ void ic_init(const float* __restrict__ x0,
                        float* __restrict__ s_, float* __restrict__ x_,
                        float* __restrict__ r_,
                        u32* __restrict__ flags, int N) {
    const int i = blockIdx.x * 256 + threadIdx.x;
    if (i < N) {
        const float v = x0[i];
        s_[i] = 1.0f - v;
        x_[i] = v;
        r_[i] = 0.0f;
    }
    if (blockIdx.x == 0 && threadIdx.x < 32)
        flags[threadIdx.x] = (threadIdx.x == 0) ? 1u : 0u;
}

// ==================== tier A scatter: one 8B store per edge ====================
__global__ __launch_bounds__(SCT8)
void ic_scatter8(const v4i* __restrict__ row4, const v4i* __restrict__ col4,
                 const v4f* __restrict__ w4,
                 u64* __restrict__ rec, u32* __restrict__ cnt, u32* __restrict__ flags,
                 u64* __restrict__ ov_rc, u32* __restrict__ ov_wb, int E4, int nblk) {
    __shared__ u32 cur[NSEG];
    if (threadIdx.x < NSEG) cur[threadIdx.x] = 0;
    __syncthreads();
    const int vbase = blockIdx.x * CHV8;
    const int vend  = min(E4, vbase + CHV8);
    for (int v = vbase + threadIdx.x; v < vend; v += SCT8) {
        const v4i rr = __builtin_nontemporal_load(row4 + v);
        const v4i cc = __builtin_nontemporal_load(col4 + v);
        const v4f ww = __builtin_nontemporal_load(w4 + v);
        #pragma unroll
        for (int u = 0; u < 4; ++u) {
            const int rw = rr[u], c = cc[u];
            const int s = c >> SEGSHIFT;
            const u32 lo = ((u32)rw << SEGSHIFT) | (u32)(c & (SEGW - 1));
            const u64 rv = ((u64)__float_as_uint(ww[u]) << 32) | lo;
            const u32 p = atomicAdd(&cur[s], 1u);
            if (p < CAP8) {
                rec[((u32)s * (u32)nblk + (u32)blockIdx.x) * CAP8 + p] = rv;
            } else {   // valve: excess records replayed by step sp==0
                const u32 oi = atomicAdd(&flags[31], 1u);
                if (oi < NOVF) {
                    ov_rc[oi] = ((u64)(u32)rw << 32) | (u32)c;
                    ov_wb[oi] = __float_as_uint(ww[u]);
                }
            }
        }
    }
    __syncthreads();
    if (threadIdx.x < NSEG)
        cnt[threadIdx.x * (u32)nblk + blockIdx.x] = min(cur[threadIdx.x], CAP8);
}

// ==================== tier A step work: round-7 loop body, NT x-gathers ====================
template<int SPL>
__device__ __forceinline__
void ic_step8_work(int s, int sp,
                   const u64* __restrict__ rec, const u32* __restrict__ cnt,
                   const float* __restrict__ x, float* __restrict__ copies,
                   const u64* __restrict__ ov_rc, const u32* __restrict__ ov_wb,
                   const u32* __restrict__ flags, int nblk, float* lagg) {
    for (int t = threadIdx.x; t < SEGW; t += 256) lagg[t] = 0.0f;
    __syncthreads();
    const int b0 = nblk * sp / SPL;
    const int b1 = nblk * (sp + 1) / SPL;
    for (int blk = b0; blk < b1; ++blk) {
        const u32 cell = (u32)s * (u32)nblk + (u32)blk;
        const u32 n = cnt[cell];
        const u64* base = rec + (size_t)cell * CAP8;
        const u32 np = n >> 1;
        for (u32 j = threadIdx.x; j < np; j += 256) {
            const v2u rp = __builtin_nontemporal_load(((const v2u*)base) + j);
            const u32 lo0 = (u32)rp[0], lo1 = (u32)rp[1];
            const float w0 = __uint_as_float((u32)(rp[0] >> 32));
            const float w1 = __uint_as_float((u32)(rp[1] >> 32));
            const float x0v = __builtin_nontemporal_load(x + (lo0 >> SEGSHIFT));
            const float x1v = __builtin_nontemporal_load(x + (lo1 >> SEGSHIFT));
            atomicAdd(&lagg[lo0 & (SEGW - 1)], __logf(fmaf(-w0, x0v, 1.0f) + 1e-15f));
            atomicAdd(&lagg[lo1 & (SEGW - 1)], __logf(fmaf(-w1, x1v, 1.0f) + 1e-15f));
        }
        if ((n & 1u) && threadIdx.x == 0) {
            const u64 rv = base[n - 1];
            const u32 lo = (u32)rv;
            const float wv = __uint_as_float((u32)(rv >> 32));
            atomicAdd(&lagg[lo & (SEGW - 1)], __logf(fmaf(-wv, x[lo >> SEGSHIFT], 1.0f) + 1e-15f));
        }
    }
    if (sp == 0) {   // replay overflow list (tens of records at most)
        const u32 nov = min(flags[31], (u32)NOVF);
        for (u32 i = threadIdx.x; i < nov; i += 256) {
            const u64 rc = ov_rc[i];
            const u32 c = (u32)rc;
            if ((int)(c >> SEGSHIFT) == s) {
                const float wv = __uint_as_float(ov_wb[i]);
                const float xv = x[(u32)(rc >> 32)];
                atomicAdd(&lagg[c & (SEGW - 1)], __logf(fmaf(-wv, xv, 1.0f) + 1e-15f));
            }
        }
    }
    __syncthreads();
    float* cp = copies + (size_t)sp * (NSEG * SEGW) + (size_t)s * SEGW;
    for (int t = threadIdx.x; t < SEGW; t += 256) cp[t] = lagg[t];
    __syncthreads();
}

template<int SPL>
__global__ __launch_bounds__(256)
void ic_step8(const u64* __restrict__ rec, const u32* __restrict__ cnt,
              const u32* __restrict__ flags, int k,
              const float* __restrict__ x, float* __restrict__ copies,
              const u64* __restrict__ ov_rc, const u32* __restrict__ ov_wb, int nblk) {
    if (flags[k] == 0) return;   // converged: q == 1.0f bit-exactly
    __shared__ float lagg[SEGW];
    const int s = blockIdx.x / SPL, sp = blockIdx.x % SPL;
    ic_step8_work<SPL>(s, sp, rec, cnt, x, copies, ov_rc, ov_wb, flags, nblk, lagg);
}

// Slim variant for k>=2 (normally flag-skipped): tiny grid, loops sp internally.
template<int SPL>
__global__ __launch_bounds__(256)
void ic_step8_slim(const u64* __restrict__ rec, const u32* __restrict__ cnt,
                   const u32* __restrict__ flags, int k,
                   const float* __restrict__ x, float* __restrict__ copies,
                   const u64* __restrict__ ov_rc, const u32* __restrict__ ov_wb, int nblk) {
    if (flags[k] == 0) return;
    __shared__ float lagg[SEGW];
    const int groups = SPL / SLIMCH;
    const int s = blockIdx.x / groups, g = blockIdx.x % groups;
    for (int sp = g * SLIMCH; sp < (g + 1) * SLIMCH; ++sp)
        ic_step8_work<SPL>(s, sp, rec, cnt, x, copies, ov_rc, ov_wb, flags, nblk, lagg);
}

// ==================== tier B (round-6): 6-byte records ====================
__global__ __launch_bounds__(SCT6)
void ic_scatter6(const v4i* __restrict__ row4, const v4i* __restrict__ col4,
                 const v4f* __restrict__ w4,
                 u32* __restrict__ lo_out, u16* __restrict__ w_out,
                 u32* __restrict__ cnt, u32* __restrict__ flags,
                 u64* __restrict__ ov_rc, u32* __restrict__ ov_wb, int E4, int nblk) {
    __shared__ u32 cur[NSEG];
    if (threadIdx.x < NSEG) cur[threadIdx.x] = 0;
    __syncthreads();
    const int vbase = blockIdx.x * CHV6;
    const int vend  = min(E4, vbase + CHV6);
    const u32 blkoff = (u32)blockIdx.x * CAP6;
    for (int v = vbase + threadIdx.x; v < vend; v += SCT6) {
        const v4i rr = __builtin_nontemporal_load(row4 + v);
        const v4i cc = __builtin_nontemporal_load(col4 + v);
        const v4f ww = __builtin_nontemporal_load(w4 + v);
        #pragma unroll
        for (int u = 0; u < 4; ++u) {
            const int rw = rr[u], c = cc[u];
            const u32 b = __float_as_uint(ww[u]);
            const u16 wh = (u16)((b + 0x7FFFu + ((b >> 16) & 1u)) >> 16);
            const int s = c >> SEGSHIFT;
            const u32 lo = ((u32)rw << SEGSHIFT) | (u32)(c & (SEGW - 1));
            const u32 p = atomicAdd(&cur[s], 1u);
            if (p < CAP6) {
                const u32 idx = ((u32)s * (u32)nblk) * CAP6 + blkoff + p;
                lo_out[idx] = lo;
                w_out[idx]  = wh;
            } else {
                const u32 oi = atomicAdd(&flags[31], 1u);
                if (oi < NOVF) {
                    ov_rc[oi] = ((u64)(u32)rw << 32) | (u32)c;
                    ov_wb[oi] = b;
                }
            }
        }
    }
    __syncthreads();
    if (threadIdx.x < NSEG)
        cnt[threadIdx.x * (u32)nblk + blockIdx.x] = min(cur[threadIdx.x], CAP6);
}

__global__ __launch_bounds__(256)
void ic_step6(const u32* __restrict__ lo_in, const u16* __restrict__ w_in,
              const u32* __restrict__ cnt, const u32* __restrict__ flags, int k,
              const float* __restrict__ x, float* __restrict__ copies,
              const u64* __restrict__ ov_rc, const u32* __restrict__ ov_wb, int nblk) {
    if (flags[k] == 0) return;
    __shared__ float lagg[SEGW];
    const int s = blockIdx.x / SPLIT6, sp = blockIdx.x % SPLIT6;
    for (int t = threadIdx.x; t < SEGW; t += 256) lagg[t] = 0.0f;
    __syncthreads();
    const int b0 = nblk * sp / SPLIT6;
    const int b1 = nblk * (sp + 1) / SPLIT6;
    for (int blk = b0; blk < b1; ++blk) {
        const u32 cell = (u32)s * (u32)nblk + (u32)blk;
        const u32 n = cnt[cell];
        const u32 base = cell * CAP6;
        for (u32 i = threadIdx.x; i < n; i += 256) {
            const u32 lo = lo_in[base + i];
            const float wv = __uint_as_float((u32)w_in[base + i] << 16);
            const float xv = x[lo >> SEGSHIFT];
            atomicAdd(&lagg[lo & (SEGW - 1)], __logf(fmaf(-wv, xv, 1.0f) + 1e-15f));
        }
    }
    if (sp == 0) {
        const u32 nov = min(flags[31], (u32)NOVF);
        for (u32 i = threadIdx.x; i < nov; i += 256) {
            const u64 rc = ov_rc[i];
            const u32 c = (u32)rc;
            if ((int)(c >> SEGSHIFT) == s) {
                const float wv = __uint_as_float(ov_wb[i]);
                const float xv = x[(u32)(rc >> 32)];
                atomicAdd(&lagg[c & (SEGW - 1)], __logf(fmaf(-wv, xv, 1.0f) + 1e-15f));
            }
        }
    }
    __syncthreads();
    float* cp = copies + (size_t)sp * (NSEG * SEGW) + (size_t)s * SEGW;
    for (int t = threadIdx.x; t < SEGW; t += 256) cp[t] = lagg[t];
}

// ============ node: q=exp(sum copies) (or 1); update s,x,r; set next flag ============
template<int NSP>
__global__ void ic_node(const float* __restrict__ copies,
                        u32* __restrict__ flags, int k,
                        float* __restrict__ s_, float* __restrict__ x_,
                        float* __restrict__ r_, int N) {
    // once two consecutive flags are 0, x is exactly 0 and updates are no-ops
    if (k > 0 && flags[k] == 0 && flags[k - 1] == 0) return;
    const int i = blockIdx.x * 256 + threadIdx.x;
    bool big = false;
    if (i < N) {
        float q;
        if (flags[k]) {
            float a = 0.0f;
            #pragma unroll
            for (int sp = 0; sp < NSP; ++sp)
                a += copies[(size_t)sp * (NSEG * SEGW) + i];
            q = expf(a);
        } else {
            q = 1.0f;
        }
        const float sv = s_[i], xv = x_[i];
        r_[i] += xv;
        const float xn = sv * (1.0f - q);
        x_[i] = xn;
        s_[i] = sv * q;
        big = (xn >= XEPS);
    }
    if (__any(big) && (threadIdx.x & 63) == 0) atomicOr(&flags[k + 1], 1u);
}

// ======================= last-resort fallback (global atomics) =======================
__global__ void ic_edge_fb(const int4* __restrict__ row4, const int4* __restrict__ col4,
                           const float4* __restrict__ w4, const float* __restrict__ x,
                           float* __restrict__ agg, int e4) {
    int i = blockIdx.x * blockDim.x + threadIdx.x;
    const int stride = gridDim.x * blockDim.x;
    for (; i < e4; i += stride) {
        int4 rr = row4[i]; int4 cc = col4[i]; float4 ww = w4[i];
        atomicAdd(&agg[cc.x], log1pf(1e-15f - ww.x * x[rr.x]));
        atomicAdd(&agg[cc.y], log1pf(1e-15f - ww.y * x[rr.y]));
        atomicAdd(&agg[cc.z], log1pf(1e-15f - ww.z * x[rr.z]));
        atomicAdd(&agg[cc.w], log1pf(1e-15f - ww.w * x[rr.w]));
    }
}
__global__ void ic_node_fb(float* __restrict__ s, float* __restrict__ x,
                           float* __restrict__ r, float* __restrict__ agg, int n) {
    const int i = blockIdx.x * blockDim.x + threadIdx.x;
    if (i < n) {
        const float q = expf(agg[i]);
        agg[i] = 0.0f;
        const float sv = s[i], xv = x[i];
        r[i] += xv;
        x[i] = sv * (1.0f - q);
        s[i] = sv * q;
    }
}
__global__ void ic_zero_fb(float* __restrict__ p, int n) {
    const int i = blockIdx.x * blockDim.x + threadIdx.x;
    if (i < n) p[i] = 0.0f;
}

// ==================================== launch ====================================
extern "C" void kernel_launch(void* const* d_in, const int* in_sizes, int n_in,
                              void* d_out, int out_size, void* d_ws, size_t ws_size,
                              hipStream_t stream) {
    const int*   ei = (const int*)d_in[0];     // [2, E]: row then col
    const float* w  = (const float*)d_in[1];   // [E]
    const float* x0 = (const float*)d_in[2];   // [N]

    const int E = in_sizes[0] / 2;
    const int N = in_sizes[2];
    const int* row = ei;
    const int* col = ei + E;

    float* s_ = (float*)d_out;
    float* x_ = s_ + N;
    float* r_ = s_ + 2 * N;

    const int nodeBlocks = (N + 255) / 256;
    const int E4 = E / 4;
    const bool shapeOK = (E == 16000000 && N == 100000);

    // ---- tier A layout (8B records); copies sized by SPLIT choice
    const size_t cells8 = (size_t)NSEG * NBLK8;                      // 25,088
    size_t a_rec = 0;
    size_t a_cnt = a_rec + cells8 * CAP8 * 8;                        // 144.5 MB
    size_t a_cp  = a_cnt + cells8 * 4;
    size_t a_cp_end_hi = a_cp + (size_t)SPLIT_HI * NSEG * SEGW * 4;  // +25.7 MB
    size_t a_cp_end_lo = a_cp + (size_t)SPLIT_LO * NSEG * SEGW * 4;  // +12.8 MB
    size_t a_ov_hi  = (a_cp_end_hi + 15) & ~(size_t)15;
    size_t a_ov_lo  = (a_cp_end_lo + 15) & ~(size_t)15;
    size_t needA_hi = a_ov_hi + (size_t)NOVF * 8 + (size_t)NOVF * 4 + 32 * 4;   // ~170.4 MB
    size_t needA_lo = a_ov_lo + (size_t)NOVF * 8 + (size_t)NOVF * 4 + 32 * 4;   // ~157.5 MB

    // ---- tier B layout (6B records)
    const int NBLK6 = (E4 + CHV6 - 1) / CHV6;                        // 489
    const size_t cells6 = (size_t)NSEG * NBLK6;
    size_t b_lo  = 0;
    size_t b_w   = b_lo + cells6 * CAP6 * 4;
    size_t b_cnt = b_w + cells6 * CAP6 * 2;
    size_t b_cp  = b_cnt + cells6 * 4;
    size_t b_ov  = (b_cp + (size_t)SPLIT6 * NSEG * SEGW * 4 + 15) & ~(size_t)15;
    size_t b_ovw = b_ov + (size_t)NOVF * 8;
    size_t b_flg = b_ovw + (size_t)NOVF * 4;
    size_t needB = b_flg + 32 * 4;                                   // ~129.5 MB

    if (shapeOK && ws_size >= needA_lo) {
        const bool hi = (ws_size >= needA_hi);
        const size_t a_ov  = hi ? a_ov_hi : a_ov_lo;
        char* ws = (char*)d_ws;
        u64* rec      = (u64*)(ws + a_rec);
        u32* cnt      = (u32*)(ws + a_cnt);
        float* copies = (float*)(ws + a_cp);
        u64* ov_rc    = (u64*)(ws + a_ov);
        u32* ov_wb    = (u32*)(ws + a_ov + (size_t)NOVF * 8);
        u32* flags    = (u32*)(ws + a_ov + (size_t)NOVF * 8 + (size_t)NOVF * 4);

        ic_init<<<nodeBlocks, 256, 0, stream>>>(x0, s_, x_, r_, flags, N);
        ic_scatter8<<<NBLK8, SCT8, 0, stream>>>(
            (const v4i*)row, (const v4i*)col, (const v4f*)w,
            rec, cnt, flags, ov_rc, ov_wb, E4, NBLK8);
        if (hi) {
            for (int k = 0; k < 10; ++k) {
                if (k < 2) {
                    ic_step8<SPLIT_HI><<<NSEG * SPLIT_HI, 256, 0, stream>>>(
                        rec, cnt, flags, k, x_, copies, ov_rc, ov_wb, NBLK8);
                } else {
                    ic_step8_slim<SPLIT_HI><<<NSEG * (SPLIT_HI / SLIMCH), 256, 0, stream>>>(
                        rec, cnt, flags, k, x_, copies, ov_rc, ov_wb, NBLK8);
                }
                ic_node<SPLIT_HI><<<nodeBlocks, 256, 0, stream>>>(copies, flags, k, s_, x_, r_, N);
            }
        } else {
            for (int k = 0; k < 10; ++k) {
                if (k < 2) {
                    ic_step8<SPLIT_LO><<<NSEG * SPLIT_LO, 256, 0, stream>>>(
                        rec, cnt, flags, k, x_, copies, ov_rc, ov_wb, NBLK8);
                } else {
                    ic_step8_slim<SPLIT_LO><<<NSEG * (SPLIT_LO / SLIMCH), 256, 0, stream>>>(
                        rec, cnt, flags, k, x_, copies, ov_rc, ov_wb, NBLK8);
                }
                ic_node<SPLIT_LO><<<nodeBlocks, 256, 0, stream>>>(copies, flags, k, s_, x_, r_, N);
            }
        }
    } else if (shapeOK && ws_size >= needB) {
        char* ws = (char*)d_ws;
        u32* lo_out   = (u32*)(ws + b_lo);
        u16* w_out    = (u16*)(ws + b_w);
        u32* cnt      = (u32*)(ws + b_cnt);
        float* copies = (float*)(ws + b_cp);
        u64* ov_rc    = (u64*)(ws + b_ov);
        u32* ov_wb    = (u32*)(ws + b_ovw);
        u32* flags    = (u32*)(ws + b_flg);

        ic_init<<<nodeBlocks, 256, 0, stream>>>(x0, s_, x_, r_, flags, N);
        ic_scatter6<<<NBLK6, SCT6, 0, stream>>>(
            (const v4i*)row, (const v4i*)col, (const v4f*)w,
            lo_out, w_out, cnt, flags, ov_rc, ov_wb, E4, NBLK6);
        for (int k = 0; k < 10; ++k) {
            ic_step6<<<NSEG * SPLIT6, 256, 0, stream>>>(
                lo_out, w_out, cnt, flags, k, x_, copies, ov_rc, ov_wb, NBLK6);
            ic_node<SPLIT6><<<nodeBlocks, 256, 0, stream>>>(copies, flags, k, s_, x_, r_, N);
        }
    } else {
        // last resort: global-atomic path (needs only N floats of ws)
        float* agg = (float*)d_ws;
        ic_init<<<nodeBlocks, 256, 0, stream>>>(x0, s_, x_, r_, (u32*)d_ws, N);
        ic_zero_fb<<<nodeBlocks, 256, 0, stream>>>(agg, N);
        const int e4 = E / 4;
        for (int step = 0; step < 10; ++step) {
            ic_edge_fb<<<2048, 256, 0, stream>>>(
                (const int4*)row, (const int4*)col, (const float4*)w, x_, agg, e4);
            ic_node_fb<<<nodeBlocks, 256, 0, stream>>>(s_, x_, r_, agg, N);
        }
    }
}

// Round 12
// 354.916 us; speedup vs baseline: 1.1853x; 1.1853x over previous
//
#include <hip/hip_runtime.h>
#include <hip/hip_bf16.h>
#include <math.h>

typedef unsigned int u32;
typedef unsigned short u16;
typedef unsigned long long u64;
typedef int   v4i __attribute__((ext_vector_type(4)));
typedef float v4f __attribute__((ext_vector_type(4)));
typedef unsigned long long v2u __attribute__((ext_vector_type(2)));

#define NSEG 49
#define SEGW 2048
#define SEGSHIFT 11
#define XEPS 1.4901161e-08f  // 2^-26: below this, q == 1.0f bit-exactly
#define NOVF 4096

// ---- tier A: 8-byte records (single dwordx2 store per edge)
#define NBLK8 512
#define CHV8 7813            // ceil(4,000,000 / 512) int4-vectors per block
#define SCT8 1024
#define CAP8 720u            // mean 637.8, +3.3 sigma; valve catches the tail
#define SPLIT8 32

// ---- tier B: 6-byte records (round-6 proven layout, smaller ws)
#define CHV6 8192
#define SCT6 512
#define CAP6 832u
#define SPLIT6 24

// ============ init: s=1-x0, x=x0, r=0; flags[0]=1, rest 0 (flags[31]=ovf cursor) ============
__global__ void ic_init(const float* __restrict__ x0,
                        float* __restrict__ s_, float* __restrict__ x_,
                        float* __restrict__ r_,
                        u32* __restrict__ flags, int N) {
    const int i = blockIdx.x * 256 + threadIdx.x;
    if (i < N) {
        const float v = x0[i];
        s_[i] = 1.0f - v;
        x_[i] = v;
        r_[i] = 0.0f;
    }
    if (blockIdx.x == 0 && threadIdx.x < 32)
        flags[threadIdx.x] = (threadIdx.x == 0) ? 1u : 0u;
}

// ==================== tier A scatter: one 8B store per edge ====================
__global__ __launch_bounds__(SCT8)
void ic_scatter8(const v4i* __restrict__ row4, const v4i* __restrict__ col4,
                 const v4f* __restrict__ w4,
                 u64* __restrict__ rec, u32* __restrict__ cnt, u32* __restrict__ flags,
                 u64* __restrict__ ov_rc, u32* __restrict__ ov_wb, int E4, int nblk) {
    __shared__ u32 cur[NSEG];
    if (threadIdx.x < NSEG) cur[threadIdx.x] = 0;
    __syncthreads();
    const int vbase = blockIdx.x * CHV8;
    const int vend  = min(E4, vbase + CHV8);
    for (int v = vbase + threadIdx.x; v < vend; v += SCT8) {
        const v4i rr = __builtin_nontemporal_load(row4 + v);
        const v4i cc = __builtin_nontemporal_load(col4 + v);
        const v4f ww = __builtin_nontemporal_load(w4 + v);
        #pragma unroll
        for (int u = 0; u < 4; ++u) {
            const int rw = rr[u], c = cc[u];
            const int s = c >> SEGSHIFT;
            const u32 lo = ((u32)rw << SEGSHIFT) | (u32)(c & (SEGW - 1));
            const u64 rv = ((u64)__float_as_uint(ww[u]) << 32) | lo;
            const u32 p = atomicAdd(&cur[s], 1u);
            if (p < CAP8) {
                rec[((u32)s * (u32)nblk + (u32)blockIdx.x) * CAP8 + p] = rv;
            } else {   // valve: excess records replayed by step sp==0
                const u32 oi = atomicAdd(&flags[31], 1u);
                if (oi < NOVF) {
                    ov_rc[oi] = ((u64)(u32)rw << 32) | (u32)c;
                    ov_wb[oi] = __float_as_uint(ww[u]);
                }
            }
        }
    }
    __syncthreads();
    if (threadIdx.x < NSEG)
        cnt[threadIdx.x * (u32)nblk + blockIdx.x] = min(cur[threadIdx.x], CAP8);
}

// ==================== tier A step: paired 16B NT loads, LDS aggregate ====================
__global__ __launch_bounds__(256)
void ic_step8(const u64* __restrict__ rec, const u32* __restrict__ cnt,
              const u32* __restrict__ flags, int k,
              const float* __restrict__ x, float* __restrict__ copies,
              const u64* __restrict__ ov_rc, const u32* __restrict__ ov_wb, int nblk) {
    if (flags[k] == 0) return;   // converged: q == 1.0f bit-exactly
    __shared__ float lagg[SEGW];
    const int s = blockIdx.x / SPLIT8, sp = blockIdx.x % SPLIT8;
    for (int t = threadIdx.x; t < SEGW; t += 256) lagg[t] = 0.0f;
    __syncthreads();
    const int b0 = nblk * sp / SPLIT8;
    const int b1 = nblk * (sp + 1) / SPLIT8;
    for (int blk = b0; blk < b1; ++blk) {
        const u32 cell = (u32)s * (u32)nblk + (u32)blk;
        const u32 n = cnt[cell];
        const u64* base = rec + (size_t)cell * CAP8;
        const u32 np = n >> 1;
        for (u32 j = threadIdx.x; j < np; j += 256) {
            const v2u rp = __builtin_nontemporal_load(((const v2u*)base) + j);
            const u32 lo0 = (u32)rp[0], lo1 = (u32)rp[1];
            const float w0 = __uint_as_float((u32)(rp[0] >> 32));
            const float w1 = __uint_as_float((u32)(rp[1] >> 32));
            const float x0v = x[lo0 >> SEGSHIFT];
            const float x1v = x[lo1 >> SEGSHIFT];
            atomicAdd(&lagg[lo0 & (SEGW - 1)], __logf(fmaf(-w0, x0v, 1.0f) + 1e-15f));
            atomicAdd(&lagg[lo1 & (SEGW - 1)], __logf(fmaf(-w1, x1v, 1.0f) + 1e-15f));
        }
        if ((n & 1u) && threadIdx.x == 0) {
            const u64 rv = base[n - 1];
            const u32 lo = (u32)rv;
            const float wv = __uint_as_float((u32)(rv >> 32));
            atomicAdd(&lagg[lo & (SEGW - 1)], __logf(fmaf(-wv, x[lo >> SEGSHIFT], 1.0f) + 1e-15f));
        }
    }
    if (sp == 0) {   // replay overflow list (tens of records)
        const u32 nov = min(flags[31], (u32)NOVF);
        for (u32 i = threadIdx.x; i < nov; i += 256) {
            const u64 rc = ov_rc[i];
            const u32 c = (u32)rc;
            if ((int)(c >> SEGSHIFT) == s) {
                const float wv = __uint_as_float(ov_wb[i]);
                const float xv = x[(u32)(rc >> 32)];
                atomicAdd(&lagg[c & (SEGW - 1)], __logf(fmaf(-wv, xv, 1.0f) + 1e-15f));
            }
        }
    }
    __syncthreads();
    float* cp = copies + (size_t)sp * (NSEG * SEGW) + (size_t)s * SEGW;
    for (int t = threadIdx.x; t < SEGW; t += 256) cp[t] = lagg[t];
}

// ==================== tier B (round-6): 6-byte records ====================
__global__ __launch_bounds__(SCT6)
void ic_scatter6(const v4i* __restrict__ row4, const v4i* __restrict__ col4,
                 const v4f* __restrict__ w4,
                 u32* __restrict__ lo_out, u16* __restrict__ w_out,
                 u32* __restrict__ cnt, u32* __restrict__ flags,
                 u64* __restrict__ ov_rc, u32* __restrict__ ov_wb, int E4, int nblk) {
    __shared__ u32 cur[NSEG];
    if (threadIdx.x < NSEG) cur[threadIdx.x] = 0;
    __syncthreads();
    const int vbase = blockIdx.x * CHV6;
    const int vend  = min(E4, vbase + CHV6);
    const u32 blkoff = (u32)blockIdx.x * CAP6;
    for (int v = vbase + threadIdx.x; v < vend; v += SCT6) {
        const v4i rr = __builtin_nontemporal_load(row4 + v);
        const v4i cc = __builtin_nontemporal_load(col4 + v);
        const v4f ww = __builtin_nontemporal_load(w4 + v);
        #pragma unroll
        for (int u = 0; u < 4; ++u) {
            const int rw = rr[u], c = cc[u];
            const u32 b = __float_as_uint(ww[u]);
            const u16 wh = (u16)((b + 0x7FFFu + ((b >> 16) & 1u)) >> 16);
            const int s = c >> SEGSHIFT;
            const u32 lo = ((u32)rw << SEGSHIFT) | (u32)(c & (SEGW - 1));
            const u32 p = atomicAdd(&cur[s], 1u);
            if (p < CAP6) {
                const u32 idx = ((u32)s * (u32)nblk) * CAP6 + blkoff + p;
                lo_out[idx] = lo;
                w_out[idx]  = wh;
            } else {
                const u32 oi = atomicAdd(&flags[31], 1u);
                if (oi < NOVF) {
                    ov_rc[oi] = ((u64)(u32)rw << 32) | (u32)c;
                    ov_wb[oi] = b;
                }
            }
        }
    }
    __syncthreads();
    if (threadIdx.x < NSEG)
        cnt[threadIdx.x * (u32)nblk + blockIdx.x] = min(cur[threadIdx.x], CAP6);
}

__global__ __launch_bounds__(256)
void ic_step6(const u32* __restrict__ lo_in, const u16* __restrict__ w_in,
              const u32* __restrict__ cnt, const u32* __restrict__ flags, int k,
              const float* __restrict__ x, float* __restrict__ copies,
              const u64* __restrict__ ov_rc, const u32* __restrict__ ov_wb, int nblk) {
    if (flags[k] == 0) return;
    __shared__ float lagg[SEGW];
    const int s = blockIdx.x / SPLIT6, sp = blockIdx.x % SPLIT6;
    for (int t = threadIdx.x; t < SEGW; t += 256) lagg[t] = 0.0f;
    __syncthreads();
    const int b0 = nblk * sp / SPLIT6;
    const int b1 = nblk * (sp + 1) / SPLIT6;
    for (int blk = b0; blk < b1; ++blk) {
        const u32 cell = (u32)s * (u32)nblk + (u32)blk;
        const u32 n = cnt[cell];
        const u32 base = cell * CAP6;
        for (u32 i = threadIdx.x; i < n; i += 256) {
            const u32 lo = lo_in[base + i];
            const float wv = __uint_as_float((u32)w_in[base + i] << 16);
            const float xv = x[lo >> SEGSHIFT];
            atomicAdd(&lagg[lo & (SEGW - 1)], __logf(fmaf(-wv, xv, 1.0f) + 1e-15f));
        }
    }
    if (sp == 0) {
        const u32 nov = min(flags[31], (u32)NOVF);
        for (u32 i = threadIdx.x; i < nov; i += 256) {
            const u64 rc = ov_rc[i];
            const u32 c = (u32)rc;
            if ((int)(c >> SEGSHIFT) == s) {
                const float wv = __uint_as_float(ov_wb[i]);
                const float xv = x[(u32)(rc >> 32)];
                atomicAdd(&lagg[c & (SEGW - 1)], __logf(fmaf(-wv, xv, 1.0f) + 1e-15f));
            }
        }
    }
    __syncthreads();
    float* cp = copies + (size_t)sp * (NSEG * SEGW) + (size_t)s * SEGW;
    for (int t = threadIdx.x; t < SEGW; t += 256) cp[t] = lagg[t];
}

// ============ node: q=exp(sum copies) (or 1); update s,x,r; set next flag ============
template<int NSP>
__global__ void ic_node(const float* __restrict__ copies,
                        u32* __restrict__ flags, int k,
                        float* __restrict__ s_, float* __restrict__ x_,
                        float* __restrict__ r_, int N) {
    // once two consecutive flags are 0, x is exactly 0 and updates are no-ops
    if (k > 0 && flags[k] == 0 && flags[k - 1] == 0) return;
    const int i = blockIdx.x * 256 + threadIdx.x;
    bool big = false;
    if (i < N) {
        float q;
        if (flags[k]) {
            float a = 0.0f;
            #pragma unroll
            for (int sp = 0; sp < NSP; ++sp)
                a += copies[(size_t)sp * (NSEG * SEGW) + i];
            q = expf(a);
        } else {
            q = 1.0f;
        }
        const float sv = s_[i], xv = x_[i];
        r_[i] += xv;
        const float xn = sv * (1.0f - q);
        x_[i] = xn;
        s_[i] = sv * q;
        big = (xn >= XEPS);
    }
    if (__any(big) && (threadIdx.x & 63) == 0) atomicOr(&flags[k + 1], 1u);
}

// ======================= last-resort fallback (global atomics) =======================
__global__ void ic_edge_fb(const int4* __restrict__ row4, const int4* __restrict__ col4,
                           const float4* __restrict__ w4, const float* __restrict__ x,
                           float* __restrict__ agg, int e4) {
    int i = blockIdx.x * blockDim.x + threadIdx.x;
    const int stride = gridDim.x * blockDim.x;
    for (; i < e4; i += stride) {
        int4 rr = row4[i]; int4 cc = col4[i]; float4 ww = w4[i];
        atomicAdd(&agg[cc.x], log1pf(1e-15f - ww.x * x[rr.x]));
        atomicAdd(&agg[cc.y], log1pf(1e-15f - ww.y * x[rr.y]));
        atomicAdd(&agg[cc.z], log1pf(1e-15f - ww.z * x[rr.z]));
        atomicAdd(&agg[cc.w], log1pf(1e-15f - ww.w * x[rr.w]));
    }
}
__global__ void ic_node_fb(float* __restrict__ s, float* __restrict__ x,
                           float* __restrict__ r, float* __restrict__ agg, int n) {
    const int i = blockIdx.x * blockDim.x + threadIdx.x;
    if (i < n) {
        const float q = expf(agg[i]);
        agg[i] = 0.0f;
        const float sv = s[i], xv = x[i];
        r[i] += xv;
        x[i] = sv * (1.0f - q);
        s[i] = sv * q;
    }
}
__global__ void ic_zero_fb(float* __restrict__ p, int n) {
    const int i = blockIdx.x * blockDim.x + threadIdx.x;
    if (i < n) p[i] = 0.0f;
}

// ==================================== launch ====================================
extern "C" void kernel_launch(void* const* d_in, const int* in_sizes, int n_in,
                              void* d_out, int out_size, void* d_ws, size_t ws_size,
                              hipStream_t stream) {
    const int*   ei = (const int*)d_in[0];     // [2, E]: row then col
    const float* w  = (const float*)d_in[1];   // [E]
    const float* x0 = (const float*)d_in[2];   // [N]

    const int E = in_sizes[0] / 2;
    const int N = in_sizes[2];
    const int* row = ei;
    const int* col = ei + E;

    float* s_ = (float*)d_out;
    float* x_ = s_ + N;
    float* r_ = s_ + 2 * N;

    const int nodeBlocks = (N + 255) / 256;
    const int E4 = E / 4;
    const bool shapeOK = (E == 16000000 && N == 100000);

    // ---- tier A layout (8B records)
    const size_t cells8 = (size_t)NSEG * NBLK8;                      // 25,088
    size_t a_rec = 0;
    size_t a_cnt = a_rec + cells8 * CAP8 * 8;                        // 144.5 MB
    size_t a_cp  = a_cnt + cells8 * 4;
    size_t a_ov  = (a_cp + (size_t)SPLIT8 * NSEG * SEGW * 4 + 15) & ~(size_t)15;
    size_t a_ovw = a_ov + (size_t)NOVF * 8;
    size_t a_flg = a_ovw + (size_t)NOVF * 4;
    size_t needA = a_flg + 32 * 4;                                   // ~157.5 MB

    // ---- tier B layout (6B records)
    const int NBLK6 = (E4 + CHV6 - 1) / CHV6;                        // 489
    const size_t cells6 = (size_t)NSEG * NBLK6;
    size_t b_lo  = 0;
    size_t b_w   = b_lo + cells6 * CAP6 * 4;
    size_t b_cnt = b_w + cells6 * CAP6 * 2;
    size_t b_cp  = b_cnt + cells6 * 4;
    size_t b_ov  = (b_cp + (size_t)SPLIT6 * NSEG * SEGW * 4 + 15) & ~(size_t)15;
    size_t b_ovw = b_ov + (size_t)NOVF * 8;
    size_t b_flg = b_ovw + (size_t)NOVF * 4;
    size_t needB = b_flg + 32 * 4;                                   // ~129.5 MB

    if (shapeOK && ws_size >= needA) {
        char* ws = (char*)d_ws;
        u64* rec      = (u64*)(ws + a_rec);
        u32* cnt      = (u32*)(ws + a_cnt);
        float* copies = (float*)(ws + a_cp);
        u64* ov_rc    = (u64*)(ws + a_ov);
        u32* ov_wb    = (u32*)(ws + a_ovw);
        u32* flags    = (u32*)(ws + a_flg);

        ic_init<<<nodeBlocks, 256, 0, stream>>>(x0, s_, x_, r_, flags, N);
        ic_scatter8<<<NBLK8, SCT8, 0, stream>>>(
            (const v4i*)row, (const v4i*)col, (const v4f*)w,
            rec, cnt, flags, ov_rc, ov_wb, E4, NBLK8);
        for (int k = 0; k < 10; ++k) {
            ic_step8<<<NSEG * SPLIT8, 256, 0, stream>>>(
                rec, cnt, flags, k, x_, copies, ov_rc, ov_wb, NBLK8);
            ic_node<SPLIT8><<<nodeBlocks, 256, 0, stream>>>(copies, flags, k, s_, x_, r_, N);
        }
    } else if (shapeOK && ws_size >= needB) {
        char* ws = (char*)d_ws;
        u32* lo_out   = (u32*)(ws + b_lo);
        u16* w_out    = (u16*)(ws + b_w);
        u32* cnt      = (u32*)(ws + b_cnt);
        float* copies = (float*)(ws + b_cp);
        u64* ov_rc    = (u64*)(ws + b_ov);
        u32* ov_wb    = (u32*)(ws + b_ovw);
        u32* flags    = (u32*)(ws + b_flg);

        ic_init<<<nodeBlocks, 256, 0, stream>>>(x0, s_, x_, r_, flags, N);
        ic_scatter6<<<NBLK6, SCT6, 0, stream>>>(
            (const v4i*)row, (const v4i*)col, (const v4f*)w,
            lo_out, w_out, cnt, flags, ov_rc, ov_wb, E4, NBLK6);
        for (int k = 0; k < 10; ++k) {
            ic_step6<<<NSEG * SPLIT6, 256, 0, stream>>>(
                lo_out, w_out, cnt, flags, k, x_, copies, ov_rc, ov_wb, NBLK6);
            ic_node<SPLIT6><<<nodeBlocks, 256, 0, stream>>>(copies, flags, k, s_, x_, r_, N);
        }
    } else {
        // last resort: global-atomic path (needs only N floats of ws)
        float* agg = (float*)d_ws;
        ic_init<<<nodeBlocks, 256, 0, stream>>>(x0, s_, x_, r_, (u32*)d_ws, N);
        ic_zero_fb<<<nodeBlocks, 256, 0, stream>>>(agg, N);
        const int e4 = E / 4;
        for (int step = 0; step < 10; ++step) {
            ic_edge_fb<<<2048, 256, 0, stream>>>(
                (const int4*)row, (const int4*)col, (const float4*)w, x_, agg, e4);
            ic_node_fb<<<nodeBlocks, 256, 0, stream>>>(s_, x_, r_, agg, N);
        }
    }
}